// Round 13
// baseline (314.426 us; speedup 1.0000x reference)
//
#include <hip/hip_runtime.h>
#include <cstdint>
#include <cstddef>

typedef unsigned short u16;
typedef unsigned int   u32;
typedef __attribute__((ext_vector_type(8))) short short8;
typedef __attribute__((ext_vector_type(4))) float floatx4;

__device__ __forceinline__ float asf(u32 u){ union{u32 u; float f;} v; v.u=u; return v.f; }
__device__ __forceinline__ u32 asu(float f){ union{float f; u32 u;} v; v.f=f; return v.u; }
__device__ __forceinline__ u16 f2bf(float f){ u32 u = asu(f); u32 r = u + 0x7FFFu + ((u>>16)&1u); return (u16)(r>>16); }
// fast bf16: round-to-nearest, ties away (2 VALU ops)
__device__ __forceinline__ u16 f2bf_fast(float f){ return (u16)((asu(f) + 0x8000u)>>16); }
__device__ __forceinline__ u32 pack2(float a, float b){ return (u32)f2bf(a) | (((u32)f2bf(b))<<16); }
__device__ __forceinline__ void bf8f(uint4 d, float* o){
  o[0]=asf(d.x<<16); o[1]=asf(d.x&0xFFFF0000u);
  o[2]=asf(d.y<<16); o[3]=asf(d.y&0xFFFF0000u);
  o[4]=asf(d.z<<16); o[5]=asf(d.z&0xFFFF0000u);
  o[6]=asf(d.w<<16); o[7]=asf(d.w&0xFFFF0000u);
}

#define SC2 0.25503485966f   // 32^-0.5 * log2(e) — folded into Q at QKV epilogue

// ---------------------------------------------------------------------------
// fp32 -> bf16 weight conversion, ALL weights in one launch.
// ---------------------------------------------------------------------------
__global__ __launch_bounds__(256) void cvt_all(
    const float* __restrict__ Wq, const float* __restrict__ Wk,
    const float* __restrict__ Wv, const float* __restrict__ Wo,
    const float* __restrict__ W1, const float* __restrict__ W2,
    u16* __restrict__ Wqkv, u16* __restrict__ Wob,
    u16* __restrict__ W1b, u16* __restrict__ W2b)
{
  const int blk = blockIdx.x;
  const float* src; u16* dst; int off;
  if      (blk < 128)  { src = Wq; dst = Wqkv;          off = blk; }
  else if (blk < 256)  { src = Wk; dst = Wqkv + 262144; off = blk - 128; }
  else if (blk < 384)  { src = Wv; dst = Wqkv + 524288; off = blk - 256; }
  else if (blk < 512)  { src = Wo; dst = Wob;           off = blk - 384; }
  else if (blk < 1024) { src = W1; dst = W1b;           off = blk - 512; }
  else                 { src = W2; dst = W2b;           off = blk - 1024; }
  const int i = (off*256 + threadIdx.x)*8;
  const float4 a = *(const float4*)(src + i);
  const float4 b = *(const float4*)(src + i + 4);
  uint4 st;
  st.x = pack2(a.x, a.y); st.y = pack2(a.z, a.w);
  st.z = pack2(b.x, b.y); st.w = pack2(b.z, b.w);
  *(uint4*)(dst + i) = st;
}

// ---------------------------------------------------------------------------
// MFMA GEMM: C[M,N] = A[M,K] @ B[N,K]^T, bf16 in, fp32 accum.
// R19 structure (verified): counted-vmcnt pipeline (T4). 3-buffer LDS,
// lookahead-1; raw s_barrier, no vmcnt(0) drain in the main loop.
// ---------------------------------------------------------------------------
enum { EPI_NONE=0, EPI_BIAS_GELU=1, EPI_BIAS_RES=2, EPI_QSCALE=3 };

template<int BM, int EPI, typename OutT>
__global__ __launch_bounds__(256) void gemm_bt(
    const u16* __restrict__ A, const u16* __restrict__ B,
    const float* __restrict__ bias, const float* __restrict__ res,
    OutT* __restrict__ C, int M, int N, int K)
{
  static_assert(BM == 64, "vmcnt literal assumes 3 loads/stage (BM=64)");
  __shared__ u16 As[3][BM*32];
  __shared__ u16 Bs[3][128*32];
  const int tid  = threadIdx.x;
  const int wave = tid >> 6;
  const int lane = tid & 63;
  const int bm = blockIdx.y, bn = blockIdx.x;

  const int srow = wave*16 + (lane>>2);
  const int scol = (lane&3)*8;
  const u16* Ag = A + (size_t)bm*BM*K;
  const u16* Bg = B + (size_t)bn*128*K;

  constexpr int WM = BM/2;          // wave M extent (32)
  constexpr int MI = WM/16;         // A-frag count (2)
  const int wm = (wave>>1)*WM;
  const int wn = (wave&1)*64;
  const int fr = lane & 15;
  const int fk = (lane>>4)*8;

  floatx4 acc[MI][4] = {};

  // 3 loads per stage: 1 x A (64 rows), 2 x B (128 rows)
  #define G_STAGE(buf, kk)                                                        \
    do {                                                                          \
      __builtin_amdgcn_global_load_lds(                                           \
          (__attribute__((address_space(1))) void*)(Ag + (size_t)srow*K + (kk) + scol), \
          (__attribute__((address_space(3))) void*)(&As[buf][wave*16*32]),        \
          16, 0, 0);                                                              \
      _Pragma("unroll")                                                           \
      for (int tt = 0; tt < 2; ++tt)                                              \
        __builtin_amdgcn_global_load_lds(                                         \
            (__attribute__((address_space(1))) void*)(Bg + (size_t)(tt*64 + srow)*K + (kk) + scol), \
            (__attribute__((address_space(3))) void*)(&Bs[buf][(tt*64 + wave*16)*32]),      \
            16, 0, 0);                                                            \
    } while (0)

  // prologue: stage k-step 0 into buf 0
  G_STAGE(0, 0);

  const int nsteps = K >> 5;
  for (int s = 0; s < nsteps; ++s) {
    const int cur = s % 3;
    if (s + 1 < nsteps) {
      G_STAGE((s+1)%3, (s+1)*32);
      // drain own stage(s) (3 oldest); stage(s+1)'s 3 loads stay in flight
      asm volatile("s_waitcnt vmcnt(3)" ::: "memory");
    } else {
      asm volatile("s_waitcnt vmcnt(0)" ::: "memory");
    }
    __builtin_amdgcn_s_barrier();           // raw: no implicit vmcnt(0) drain
    __builtin_amdgcn_sched_barrier(0);      // pin: no ds_read hoisted above

    short8 af[MI], bfr[4];
    #pragma unroll
    for (int i=0;i<MI;i++) af[i] = *(const short8*)(&As[cur][(wm + i*16 + fr)*32 + fk]);
    #pragma unroll
    for (int j=0;j<4;j++) bfr[j] = *(const short8*)(&Bs[cur][(wn + j*16 + fr)*32 + fk]);
    #pragma unroll
    for (int i=0;i<MI;i++)
      #pragma unroll
      for (int j=0;j<4;j++)
        acc[i][j] = __builtin_amdgcn_mfma_f32_16x16x32_bf16(af[i], bfr[j], acc[i][j], 0, 0, 0);
  }
  #undef G_STAGE

  const int col0 = bn*128 + wn + fr;
  float bv[4] = {0.f,0.f,0.f,0.f};
  if constexpr (EPI == EPI_BIAS_GELU || EPI == EPI_BIAS_RES) {
    #pragma unroll
    for (int j=0;j<4;j++) bv[j] = bias[col0 + j*16];
  }
  const int rq = (lane>>4)*4;
  #pragma unroll
  for (int i=0;i<MI;i++){
    #pragma unroll
    for (int rr=0;rr<4;rr++){
      const int m = bm*BM + wm + i*16 + rq + rr;
      const size_t rowoff = (size_t)m*N;
      #pragma unroll
      for (int j=0;j<4;j++){
        float vv = acc[i][j][rr];
        const int n = col0 + j*16;
        if constexpr (EPI == EPI_BIAS_GELU){
          vv += bv[j];
          vv = 0.5f*vv*(1.f + erff(vv*0.70710678118654752f));
        } else if constexpr (EPI == EPI_BIAS_RES){
          vv += bv[j] + res[rowoff + n];
        } else if constexpr (EPI == EPI_QSCALE){
          if (n < 512) vv *= SC2;   // pre-scale Q so attn uses exp2 directly
        }
        if constexpr (sizeof(OutT) == 2) C[rowoff + n] = f2bf(vv);
        else                             C[rowoff + n] = vv;
      }
    }
  }
}

// ---------------------------------------------------------------------------
// LayerNorm over 512 (fp32 in, bf16 out), wave-per-row, 4 rows/block
// ---------------------------------------------------------------------------
__global__ __launch_bounds__(256) void ln512_kernel(
    const float* __restrict__ x, const float* __restrict__ w, const float* __restrict__ b,
    u16* __restrict__ out)
{
  const int row  = blockIdx.x*4 + (threadIdx.x>>6);
  const int lane = threadIdx.x & 63;
  const size_t base = (size_t)row*512 + lane*8;
  float v[8];
  { const float4 a = *(const float4*)(x + base);
    const float4 c = *(const float4*)(x + base + 4);
    v[0]=a.x; v[1]=a.y; v[2]=a.z; v[3]=a.w; v[4]=c.x; v[5]=c.y; v[6]=c.z; v[7]=c.w; }
  float s=0.f, sq=0.f;
  #pragma unroll
  for (int i=0;i<8;i++){ s += v[i]; sq += v[i]*v[i]; }
  for (int off=32; off>0; off>>=1){ s += __shfl_xor(s, off, 64); sq += __shfl_xor(sq, off, 64); }
  const float mu = s*(1.f/512.f);
  const float rs = rsqrtf(sq*(1.f/512.f) - mu*mu + 1e-5f);
  float o[8];
  #pragma unroll
  for (int i=0;i<8;i++)
    o[i] = (v[i]-mu)*rs*w[lane*8+i] + b[lane*8+i];
  uint4 st; st.x=pack2(o[0],o[1]); st.y=pack2(o[2],o[3]); st.z=pack2(o[4],o[5]); st.w=pack2(o[6],o[7]);
  *(uint4*)(out + base) = st;
}

// h = LN(ao)*w2+b2 + x (fp32 out) ; z = LN(h)*w3+b3 (bf16 out)
__global__ __launch_bounds__(256) void lnres_kernel(
    const u16* __restrict__ ao, const float* __restrict__ x,
    const float* __restrict__ w2, const float* __restrict__ b2,
    const float* __restrict__ w3, const float* __restrict__ b3,
    float* __restrict__ h, u16* __restrict__ z)
{
  const int row  = blockIdx.x*4 + (threadIdx.x>>6);
  const int lane = threadIdx.x & 63;
  const size_t base = (size_t)row*512 + lane*8;
  float a[8], xr[8];
  bf8f(*(const uint4*)(ao + base), a);
  { const float4 p = *(const float4*)(x + base);
    const float4 q = *(const float4*)(x + base + 4);
    xr[0]=p.x; xr[1]=p.y; xr[2]=p.z; xr[3]=p.w; xr[4]=q.x; xr[5]=q.y; xr[6]=q.z; xr[7]=q.w; }
  float s=0.f, sq=0.f;
  #pragma unroll
  for (int i=0;i<8;i++){ s += a[i]; sq += a[i]*a[i]; }
  for (int off=32; off>0; off>>=1){ s += __shfl_xor(s, off, 64); sq += __shfl_xor(sq, off, 64); }
  float mu = s*(1.f/512.f);
  float rs = rsqrtf(sq*(1.f/512.f) - mu*mu + 1e-5f);
  float hv[8];
  #pragma unroll
  for (int i=0;i<8;i++)
    hv[i] = (a[i]-mu)*rs*w2[lane*8+i] + b2[lane*8+i] + xr[i];
  { float4 p; p.x=hv[0]; p.y=hv[1]; p.z=hv[2]; p.w=hv[3];
    float4 q; q.x=hv[4]; q.y=hv[5]; q.z=hv[6]; q.w=hv[7];
    *(float4*)(h + base) = p; *(float4*)(h + base + 4) = q; }
  s=0.f; sq=0.f;
  #pragma unroll
  for (int i=0;i<8;i++){ s += hv[i]; sq += hv[i]*hv[i]; }
  for (int off=32; off>0; off>>=1){ s += __shfl_xor(s, off, 64); sq += __shfl_xor(sq, off, 64); }
  mu = s*(1.f/512.f);
  rs = rsqrtf(sq*(1.f/512.f) - mu*mu + 1e-5f);
  float zv[8];
  #pragma unroll
  for (int i=0;i<8;i++)
    zv[i] = (hv[i]-mu)*rs*w3[lane*8+i] + b3[lane*8+i];
  uint4 st; st.x=pack2(zv[0],zv[1]); st.y=pack2(zv[2],zv[3]); st.z=pack2(zv[4],zv[5]); st.w=pack2(zv[6],zv[7]);
  *(uint4*)(z + base) = st;
}

// LayerNorm over 2048 (bf16, in place safe)
__global__ __launch_bounds__(256) void ln2048_kernel(
    const u16* x, const float* __restrict__ w, const float* __restrict__ b,
    u16* out)
{
  const int row  = blockIdx.x*4 + (threadIdx.x>>6);
  const int lane = threadIdx.x & 63;
  const u16* xp = x + (size_t)row*2048;
  float v[32];
  #pragma unroll
  for (int g=0; g<4; ++g) bf8f(*(const uint4*)(xp + g*512 + lane*8), v + g*8);
  float s=0.f, sq=0.f;
  #pragma unroll
  for (int i=0;i<32;i++){ s += v[i]; sq += v[i]*v[i]; }
  for (int off=32; off>0; off>>=1){ s += __shfl_xor(s, off, 64); sq += __shfl_xor(sq, off, 64); }
  const float mu = s*(1.f/2048.f);
  const float rs = rsqrtf(sq*(1.f/2048.f) - mu*mu + 1e-5f);
  u16* op = out + (size_t)row*2048;
  #pragma unroll
  for (int g=0; g<4; ++g){
    float o[8];
    #pragma unroll
    for (int i=0;i<8;i++){
      const int idx = g*512 + lane*8 + i;
      o[i] = (v[g*8+i]-mu)*rs*w[idx] + b[idx];
    }
    uint4 st; st.x=pack2(o[0],o[1]); st.y=pack2(o[2],o[3]); st.z=pack2(o[4],o[5]); st.w=pack2(o[6],o[7]);
    *(uint4*)(op + g*512 + lane*8) = st;
  }
}

// ---------------------------------------------------------------------------
// V transpose: QKV[8192 tok][1536] (v at col 1024) -> Vt[bh 64][dim 64][key 1024].
// ---------------------------------------------------------------------------
__global__ __launch_bounds__(256) void transpose_v(
    const u16* __restrict__ QKV, u16* __restrict__ Vt)
{
  __shared__ __align__(16) u16 T[64][72];
  const int bid = blockIdx.x;
  const int bh  = bid >> 4;
  const int kt  = bid & 15;
  const int b   = bh >> 3;
  const int h   = bh & 7;
  const int tid = threadIdx.x;

  const int key = tid >> 2;
  const int dc  = (tid & 3) * 16;
  const u16* src = QKV + ((size_t)(b*1024 + kt*64 + key))*1536 + 1024 + h*64 + dc;
  const uint4 a0 = *(const uint4*)(src);
  const uint4 a1 = *(const uint4*)(src + 8);
  *(uint4*)(&T[key][dc])     = a0;
  *(uint4*)(&T[key][dc + 8]) = a1;
  __syncthreads();

  const int d  = tid >> 2;
  const int kc = (tid & 3) * 16;
  union { uint4 q[2]; u16 us[16]; } ow;
  #pragma unroll
  for (int i=0;i<16;i++) ow.us[i] = T[kc + i][d];
  u16* dst = Vt + ((size_t)(bh*64 + d))*1024 + kt*64 + kc;
  *(uint4*)(dst)     = ow.q[0];
  *(uint4*)(dst + 8) = ow.q[1];
}

// ---------------------------------------------------------------------------
// MFMA differential flash attention — R20: R18/R19 structure (verified),
// with Ps shrunk 8 KB -> 4 KB: ONE wave-private P buffer time-shared
// between the two subs (write P1 -> read ap1 -> write P2 same addrs ->
// read ap2; per-wave in-order DS ops make this safe — same precedent as
// the cross-kh buffer reuse). LDS 40960 -> 36864 B: 4 blocks/CU with
// margin (was exactly 4x40960 = 163840 = full LDS, residency-fragile).
// Epilogue f2bf -> f2bf_fast.
// ---------------------------------------------------------------------------
__global__ __launch_bounds__(256) void attn_mfma(
    const u16* __restrict__ QKV, const u16* __restrict__ Vt,
    const float* __restrict__ lq1, const float* __restrict__ lk1,
    const float* __restrict__ lq2, const float* __restrict__ lk2,
    const float* __restrict__ subw, u16* __restrict__ out)
{
  __shared__ __align__(16) u16 Ks1[2][64*32];   // [buf][key][dim 0..31]  8 KB
  __shared__ __align__(16) u16 Ks2[2][64*32];   // [buf][key][dim 32..63] 8 KB
  __shared__ __align__(16) u16 Vs [2][64*64];   // [buf][dim][key 0..63] 16 KB
  __shared__ __align__(16) u16 Ps [4][16*32];   // [wave][row*32]         4 KB

  const int tid  = threadIdx.x;
  const int wave = tid >> 6;
  const int lane = tid & 63;
  const int quad = lane >> 4;
  const int l15  = lane & 15;

  // XCD-chunked swizzle (T1, verified R16: FETCH 69.7->12.4 MB)
  const int bid = blockIdx.x;
  const int bh  = (bid & 7)*8 + ((bid >> 3) >> 4);
  const int qt  = (bid >> 3) & 15;
  const int b   = bh >> 3;
  const int h   = bh & 7;

  float t1 = 0.f, t2 = 0.f;
  for (int i=0;i<32;i++){ t1 += lq1[i]*lk1[i]; t2 += lq2[i]*lk2[i]; }
  const float lam = __expf(t1) - __expf(t2) + 0.2f;   // LAMBDA_INIT = 0.2

  const int qrowg = b*1024 + qt*64 + wave*16 + l15;
  const short8 aq1 = *(const short8*)(QKV + (size_t)qrowg*1536 + 2*h*32 + quad*8);
  const short8 aq2 = *(const short8*)(QKV + (size_t)qrowg*1536 + 2*h*32 + 32 + quad*8);

  floatx4 O1[4] = {}, O2[4] = {};
  float l1acc[4] = {0.f,0.f,0.f,0.f};
  float l2acc[4] = {0.f,0.f,0.f,0.f};
  const floatx4 zf4 = {0.f,0.f,0.f,0.f};

  const int kvbase = b*1024;
  u16* pw = &Ps[wave][0];

  const int kchunk = ((lane&3) ^ ((lane>>3)&3)) * 8;
  const u16* KbaseS = QKV + (size_t)(kvbase + wave*16 + (lane>>2))*1536 + 512 + 2*h*32 + kchunk;
  const int vchunk = ((lane&7) ^ (lane>>3)) * 8;
  const u16* VbaseS = Vt + ((size_t)bh*64 + wave*16 + (lane>>3))*1024 + vchunk;

  #define STAGE_TILE(buf, tt)                                                     \
    do {                                                                          \
      const u16* kp = KbaseS + (size_t)(tt)*64*1536;                              \
      __builtin_amdgcn_global_load_lds(                                           \
          (__attribute__((address_space(1))) void*)(kp),                          \
          (__attribute__((address_space(3))) void*)(&Ks1[buf][wave*16*32]), 16, 0, 0); \
      __builtin_amdgcn_global_load_lds(                                           \
          (__attribute__((address_space(1))) void*)(kp + 32),                     \
          (__attribute__((address_space(3))) void*)(&Ks2[buf][wave*16*32]), 16, 0, 0); \
      const u16* vp = VbaseS + (tt)*64;                                           \
      __builtin_amdgcn_global_load_lds(                                           \
          (__attribute__((address_space(1))) void*)(vp),                          \
          (__attribute__((address_space(3))) void*)(&Vs[buf][wave*16*64]), 16, 0, 0); \
      __builtin_amdgcn_global_load_lds(                                           \
          (__attribute__((address_space(1))) void*)(vp + (size_t)8*1024),         \
          (__attribute__((address_space(3))) void*)(&Vs[buf][(wave*16+8)*64]), 16, 0, 0); \
    } while (0)

  STAGE_TILE(0, 0);
  __syncthreads();

  const int kslotR = (quad ^ ((l15>>1)&3)) * 8;
  const int pslotR = ((quad + (l15>>2)) & 3) * 8;

  for (int t = 0; t < 16; ++t) {
    const int cur = t & 1;

    if (t < 15) STAGE_TILE(cur^1, t+1);

    #pragma unroll
    for (int kh = 0; kh < 2; ++kh) {
      u32 p2h[4];
      #pragma unroll
      for (int ktl = 0; ktl < 2; ++ktl) {
        const int kt = kh*2 + ktl;
        const short8 bk1 = *(const short8*)(&Ks1[cur][(kt*16 + l15)*32 + kslotR]);
        const short8 bk2 = *(const short8*)(&Ks2[cur][(kt*16 + l15)*32 + kslotR]);
        const floatx4 s1 = __builtin_amdgcn_mfma_f32_16x16x32_bf16(aq1, bk1, zf4, 0, 0, 0);
        const floatx4 s2 = __builtin_amdgcn_mfma_f32_16x16x32_bf16(aq2, bk2, zf4, 0, 0, 0);
        const int wslot = ((ktl*2 + (l15>>3) + quad) & 3)*8;
        u16* d1 = pw + wslot + (l15&7);
        float p2v[4];
        #pragma unroll
        for (int rr = 0; rr < 4; ++rr) {
          const float p1 = __builtin_amdgcn_exp2f(s1[rr]);  // Q pre-scaled by SC2
          const float p2 = __builtin_amdgcn_exp2f(s2[rr]);
          d1[(quad*4+rr)*32] = f2bf_fast(p1);
          l1acc[rr] += p1;
          l2acc[rr] += p2;
          p2v[rr] = p2;
        }
        p2h[ktl*2+0] = (u32)f2bf_fast(p2v[0]) | ((u32)f2bf_fast(p2v[1])<<16);
        p2h[ktl*2+1] = (u32)f2bf_fast(p2v[2]) | ((u32)f2bf_fast(p2v[3])<<16);
      }
      // read sub1 A-frag (in-order DS: completes before the P2 overwrites)
      const short8 ap1 = *(const short8*)(pw + l15*32 + pslotR);
      // write sub2 P into the SAME buffer
      #pragma unroll
      for (int ktl = 0; ktl < 2; ++ktl) {
        const int wslot = ((ktl*2 + (l15>>3) + quad) & 3)*8;
        u16* d2 = pw + wslot + (l15&7);
        d2[(quad*4+0)*32] = (u16)(p2h[ktl*2+0] & 0xFFFFu);
        d2[(quad*4+1)*32] = (u16)(p2h[ktl*2+0] >> 16);
        d2[(quad*4+2)*32] = (u16)(p2h[ktl*2+1] & 0xFFFFu);
        d2[(quad*4+3)*32] = (u16)(p2h[ktl*2+1] >> 16);
      }
      const short8 ap2 = *(const short8*)(pw + l15*32 + pslotR);
      const int vslotR = ((kh*4 + quad) ^ (l15&7)) * 8;
      #pragma unroll
      for (int nt = 0; nt < 4; ++nt) {
        const short8 bv = *(const short8*)(&Vs[cur][(nt*16 + l15)*64 + vslotR]);
        O1[nt] = __builtin_amdgcn_mfma_f32_16x16x32_bf16(ap1, bv, O1[nt], 0, 0, 0);
        O2[nt] = __builtin_amdgcn_mfma_f32_16x16x32_bf16(ap2, bv, O2[nt], 0, 0, 0);
      }
    }

    if (t < 15) __syncthreads();
  }
  #undef STAGE_TILE

  #pragma unroll
  for (int rr=0; rr<4; ++rr){
    float v1 = l1acc[rr], v2 = l2acc[rr];
    v1 += __shfl_xor(v1, 1, 64); v2 += __shfl_xor(v2, 1, 64);
    v1 += __shfl_xor(v1, 2, 64); v2 += __shfl_xor(v2, 2, 64);
    v1 += __shfl_xor(v1, 4, 64); v2 += __shfl_xor(v2, 4, 64);
    v1 += __shfl_xor(v1, 8, 64); v2 += __shfl_xor(v2, 8, 64);
    l1acc[rr] = v1; l2acc[rr] = v2;
  }

  float sw[4];
  #pragma unroll
  for (int nt=0; nt<4; ++nt) sw[nt] = subw[nt*16 + l15];

  #pragma unroll
  for (int rr=0; rr<4; ++rr){
    const int row = quad*4 + rr;
    const float il1 = 1.f / l1acc[rr];
    const float cl2 = lam / l2acc[rr];
    float o[4]; float ss = 0.f;
    #pragma unroll
    for (int nt=0; nt<4; ++nt){
      o[nt] = O1[nt][rr]*il1 - O2[nt][rr]*cl2;
      ss += o[nt]*o[nt];
    }
    ss += __shfl_xor(ss, 1, 64);
    ss += __shfl_xor(ss, 2, 64);
    ss += __shfl_xor(ss, 4, 64);
    ss += __shfl_xor(ss, 8, 64);
    const float rs = rsqrtf(ss*(1.f/64.f) + 1e-5f) * 0.8f;
    const int orow = b*1024 + qt*64 + wave*16 + row;
    u16* op = out + (size_t)orow*512 + h*64 + l15;
    #pragma unroll
    for (int nt=0; nt<4; ++nt)
      op[nt*16] = f2bf_fast(o[nt]*rs*sw[nt]);
  }
}

// ---------------------------------------------------------------------------
extern "C" void kernel_launch(void* const* d_in, const int* in_sizes, int n_in,
                              void* d_out, int out_size, void* d_ws, size_t ws_size,
                              hipStream_t stream)
{
  (void)in_sizes; (void)n_in; (void)out_size; (void)ws_size;
  const float* x    = (const float*)d_in[0];
  const float* Wq   = (const float*)d_in[1];
  const float* Wk   = (const float*)d_in[2];
  const float* Wv   = (const float*)d_in[3];
  const float* Wo   = (const float*)d_in[4];
  const float* lq1  = (const float*)d_in[5];
  const float* lk1  = (const float*)d_in[6];
  const float* lq2  = (const float*)d_in[7];
  const float* lk2  = (const float*)d_in[8];
  const float* subw = (const float*)d_in[9];
  const float* n1w  = (const float*)d_in[10];
  const float* n1b  = (const float*)d_in[11];
  const float* n2w  = (const float*)d_in[12];
  const float* n2b  = (const float*)d_in[13];
  const float* m1w  = (const float*)d_in[14];
  const float* m1b  = (const float*)d_in[15];
  const float* mW1  = (const float*)d_in[16];
  const float* mb1  = (const float*)d_in[17];
  const float* m2w  = (const float*)d_in[18];
  const float* m2b  = (const float*)d_in[19];
  const float* mW2  = (const float*)d_in[20];
  const float* mb2  = (const float*)d_in[21];
  float* out = (float*)d_out;   // fp32 output

  char* ws = (char*)d_ws;
  const size_t MB = (size_t)1 << 20;
  u16*  xn  = (u16*)(ws + 0*MB);
  u16*  qkv = (u16*)(ws + 8*MB);    // [8192][1536] bf16 = 24 MB -> [8,32)
  u16*  a   = (u16*)(ws + 0*MB);    // attn out, reuse xn
  u16*  ao  = (u16*)(ws + 8*MB);    // reuse qkv (dead after attn)
  u16*  z1  = (u16*)(ws + 16*MB);
  float* h  = (float*)(ws + 32*MB);
  u16*  vt  = (u16*)(ws + 32*MB);   // Vt[64][64][1024]; dead before h written
  u16*  t   = (u16*)(ws + 48*MB);   // [48,80), LN2048 in place
  u16* Wqkvb= (u16*)(ws + 80*MB);   // [1536][512] bf16 = 1.5 MB
  u16* Wob  = (u16*)(ws + 81*MB + 512*1024);
  u16* W1b  = (u16*)(ws + 82*MB);
  u16* W2b  = (u16*)(ws + 84*MB);

  const int M = 8192;

  cvt_all<<<1536, 256, 0, stream>>>(Wq, Wk, Wv, Wo, mW1, mW2, Wqkvb, Wob, W1b, W2b);

  ln512_kernel<<<2048, 256, 0, stream>>>(x, n1w, n1b, xn);

  gemm_bt<64,EPI_QSCALE,u16><<<dim3(12,128), 256, 0, stream>>>(xn, Wqkvb, nullptr, nullptr, qkv, M, 1536, 512);

  transpose_v<<<1024, 256, 0, stream>>>(qkv, vt);

  attn_mfma<<<1024, 256, 0, stream>>>(qkv, vt, lq1, lk1, lq2, lk2, subw, a);

  gemm_bt<64,EPI_NONE,u16><<<dim3(4,128), 256, 0, stream>>>(a, Wob, nullptr, nullptr, ao, M, 512, 512);

  lnres_kernel<<<2048, 256, 0, stream>>>(ao, x, n2w, n2b, m1w, m1b, h, z1);

  gemm_bt<64,EPI_BIAS_GELU,u16><<<dim3(16,128), 256, 0, stream>>>(z1, W1b, mb1, nullptr, t, M, 2048, 512);

  ln2048_kernel<<<2048, 256, 0, stream>>>(t, m2w, m2b, t);

  gemm_bt<64,EPI_BIAS_RES,float><<<dim3(4,128), 256, 0, stream>>>(t, W2b, mb2, h, out, M, 512, 2048);
}

// Round 14
// 311.478 us; speedup vs baseline: 1.0095x; 1.0095x over previous
//
#include <hip/hip_runtime.h>
#include <cstdint>
#include <cstddef>

typedef unsigned short u16;
typedef unsigned int   u32;
typedef __attribute__((ext_vector_type(8))) short short8;
typedef __attribute__((ext_vector_type(4))) float floatx4;

__device__ __forceinline__ float asf(u32 u){ union{u32 u; float f;} v; v.u=u; return v.f; }
__device__ __forceinline__ u32 asu(float f){ union{float f; u32 u;} v; v.f=f; return v.u; }
__device__ __forceinline__ float bf2f(u16 u){ return asf(((u32)u)<<16); }
__device__ __forceinline__ u16 f2bf(float f){ u32 u = asu(f); u32 r = u + 0x7FFFu + ((u>>16)&1u); return (u16)(r>>16); }
// fast bf16: round-to-nearest, ties away (2 VALU ops)
__device__ __forceinline__ u16 f2bf_fast(float f){ return (u16)((asu(f) + 0x8000u)>>16); }
__device__ __forceinline__ u32 pack2(float a, float b){ return (u32)f2bf(a) | (((u32)f2bf(b))<<16); }
__device__ __forceinline__ void bf8f(uint4 d, float* o){
  o[0]=asf(d.x<<16); o[1]=asf(d.x&0xFFFF0000u);
  o[2]=asf(d.y<<16); o[3]=asf(d.y&0xFFFF0000u);
  o[4]=asf(d.z<<16); o[5]=asf(d.z&0xFFFF0000u);
  o[6]=asf(d.w<<16); o[7]=asf(d.w&0xFFFF0000u);
}
// tanh-form GELU via bare v_exp_f32 (max err ~3e-4 vs exact; clamp avoids inf/inf)
__device__ __forceinline__ float gelu_fast(float x){
  const float t = fminf(2.30220771f*(x + 0.044715f*x*x*x), 126.f);
  const float e = __builtin_amdgcn_exp2f(t);
  return x * e / (e + 1.f);
}

#define SC2 0.25503485966f   // 32^-0.5 * log2(e) — folded into Q at QKV epilogue

// ---------------------------------------------------------------------------
// fp32 -> bf16 weight conversion, ALL weights in one launch.
// ---------------------------------------------------------------------------
__global__ __launch_bounds__(256) void cvt_all(
    const float* __restrict__ Wq, const float* __restrict__ Wk,
    const float* __restrict__ Wv, const float* __restrict__ Wo,
    const float* __restrict__ W1, const float* __restrict__ W2,
    u16* __restrict__ Wqkv, u16* __restrict__ Wob,
    u16* __restrict__ W1b, u16* __restrict__ W2b)
{
  const int blk = blockIdx.x;
  const float* src; u16* dst; int off;
  if      (blk < 128)  { src = Wq; dst = Wqkv;          off = blk; }
  else if (blk < 256)  { src = Wk; dst = Wqkv + 262144; off = blk - 128; }
  else if (blk < 384)  { src = Wv; dst = Wqkv + 524288; off = blk - 256; }
  else if (blk < 512)  { src = Wo; dst = Wob;           off = blk - 384; }
  else if (blk < 1024) { src = W1; dst = W1b;           off = blk - 512; }
  else                 { src = W2; dst = W2b;           off = blk - 1024; }
  const int i = (off*256 + threadIdx.x)*8;
  const float4 a = *(const float4*)(src + i);
  const float4 b = *(const float4*)(src + i + 4);
  uint4 st;
  st.x = pack2(a.x, a.y); st.y = pack2(a.z, a.w);
  st.z = pack2(b.x, b.y); st.w = pack2(b.z, b.w);
  *(uint4*)(dst + i) = st;
}

// ---------------------------------------------------------------------------
// MFMA GEMM: C[M,N] = A[M,K] @ B[N,K]^T, bf16 in, fp32 accum.
// R19 structure (verified): counted-vmcnt pipeline (T4). 3-buffer LDS,
// lookahead-1; raw s_barrier, no vmcnt(0) drain in the main loop.
// R21 epilogue changes: EPI_BIAS_GELU uses gelu_fast (erff was a ~30-op
// libm call x 16.8M outputs); EPI_BIAS_RES reads the residual as bf16.
// ---------------------------------------------------------------------------
enum { EPI_NONE=0, EPI_BIAS_GELU=1, EPI_BIAS_RES=2, EPI_QSCALE=3 };

template<int BM, int EPI, typename OutT>
__global__ __launch_bounds__(256) void gemm_bt(
    const u16* __restrict__ A, const u16* __restrict__ B,
    const float* __restrict__ bias, const void* __restrict__ res,
    OutT* __restrict__ C, int M, int N, int K)
{
  static_assert(BM == 64, "vmcnt literal assumes 3 loads/stage (BM=64)");
  __shared__ u16 As[3][BM*32];
  __shared__ u16 Bs[3][128*32];
  const int tid  = threadIdx.x;
  const int wave = tid >> 6;
  const int lane = tid & 63;
  const int bm = blockIdx.y, bn = blockIdx.x;

  const int srow = wave*16 + (lane>>2);
  const int scol = (lane&3)*8;
  const u16* Ag = A + (size_t)bm*BM*K;
  const u16* Bg = B + (size_t)bn*128*K;

  constexpr int WM = BM/2;          // wave M extent (32)
  constexpr int MI = WM/16;         // A-frag count (2)
  const int wm = (wave>>1)*WM;
  const int wn = (wave&1)*64;
  const int fr = lane & 15;
  const int fk = (lane>>4)*8;

  floatx4 acc[MI][4] = {};

  // 3 loads per stage: 1 x A (64 rows), 2 x B (128 rows)
  #define G_STAGE(buf, kk)                                                        \
    do {                                                                          \
      __builtin_amdgcn_global_load_lds(                                           \
          (__attribute__((address_space(1))) void*)(Ag + (size_t)srow*K + (kk) + scol), \
          (__attribute__((address_space(3))) void*)(&As[buf][wave*16*32]),        \
          16, 0, 0);                                                              \
      _Pragma("unroll")                                                           \
      for (int tt = 0; tt < 2; ++tt)                                              \
        __builtin_amdgcn_global_load_lds(                                         \
            (__attribute__((address_space(1))) void*)(Bg + (size_t)(tt*64 + srow)*K + (kk) + scol), \
            (__attribute__((address_space(3))) void*)(&Bs[buf][(tt*64 + wave*16)*32]),      \
            16, 0, 0);                                                            \
    } while (0)

  // prologue: stage k-step 0 into buf 0
  G_STAGE(0, 0);

  const int nsteps = K >> 5;
  for (int s = 0; s < nsteps; ++s) {
    const int cur = s % 3;
    if (s + 1 < nsteps) {
      G_STAGE((s+1)%3, (s+1)*32);
      // drain own stage(s) (3 oldest); stage(s+1)'s 3 loads stay in flight
      asm volatile("s_waitcnt vmcnt(3)" ::: "memory");
    } else {
      asm volatile("s_waitcnt vmcnt(0)" ::: "memory");
    }
    __builtin_amdgcn_s_barrier();           // raw: no implicit vmcnt(0) drain
    __builtin_amdgcn_sched_barrier(0);      // pin: no ds_read hoisted above

    short8 af[MI], bfr[4];
    #pragma unroll
    for (int i=0;i<MI;i++) af[i] = *(const short8*)(&As[cur][(wm + i*16 + fr)*32 + fk]);
    #pragma unroll
    for (int j=0;j<4;j++) bfr[j] = *(const short8*)(&Bs[cur][(wn + j*16 + fr)*32 + fk]);
    #pragma unroll
    for (int i=0;i<MI;i++)
      #pragma unroll
      for (int j=0;j<4;j++)
        acc[i][j] = __builtin_amdgcn_mfma_f32_16x16x32_bf16(af[i], bfr[j], acc[i][j], 0, 0, 0);
  }
  #undef G_STAGE

  const int col0 = bn*128 + wn + fr;
  float bv[4] = {0.f,0.f,0.f,0.f};
  if constexpr (EPI == EPI_BIAS_GELU || EPI == EPI_BIAS_RES) {
    #pragma unroll
    for (int j=0;j<4;j++) bv[j] = bias[col0 + j*16];
  }
  const u16* r16 = (const u16*)res;
  const int rq = (lane>>4)*4;
  #pragma unroll
  for (int i=0;i<MI;i++){
    #pragma unroll
    for (int rr=0;rr<4;rr++){
      const int m = bm*BM + wm + i*16 + rq + rr;
      const size_t rowoff = (size_t)m*N;
      #pragma unroll
      for (int j=0;j<4;j++){
        float vv = acc[i][j][rr];
        const int n = col0 + j*16;
        if constexpr (EPI == EPI_BIAS_GELU){
          vv = gelu_fast(vv + bv[j]);
        } else if constexpr (EPI == EPI_BIAS_RES){
          vv += bv[j] + bf2f(r16[rowoff + n]);
        } else if constexpr (EPI == EPI_QSCALE){
          if (n < 512) vv *= SC2;   // pre-scale Q so attn uses exp2 directly
        }
        if constexpr (sizeof(OutT) == 2) C[rowoff + n] = f2bf(vv);
        else                             C[rowoff + n] = vv;
      }
    }
  }
}

// ---------------------------------------------------------------------------
// LayerNorm over 512 (fp32 in, bf16 out), wave-per-row, 4 rows/block
// ---------------------------------------------------------------------------
__global__ __launch_bounds__(256) void ln512_kernel(
    const float* __restrict__ x, const float* __restrict__ w, const float* __restrict__ b,
    u16* __restrict__ out)
{
  const int row  = blockIdx.x*4 + (threadIdx.x>>6);
  const int lane = threadIdx.x & 63;
  const size_t base = (size_t)row*512 + lane*8;
  float v[8];
  { const float4 a = *(const float4*)(x + base);
    const float4 c = *(const float4*)(x + base + 4);
    v[0]=a.x; v[1]=a.y; v[2]=a.z; v[3]=a.w; v[4]=c.x; v[5]=c.y; v[6]=c.z; v[7]=c.w; }
  float s=0.f, sq=0.f;
  #pragma unroll
  for (int i=0;i<8;i++){ s += v[i]; sq += v[i]*v[i]; }
  for (int off=32; off>0; off>>=1){ s += __shfl_xor(s, off, 64); sq += __shfl_xor(sq, off, 64); }
  const float mu = s*(1.f/512.f);
  const float rs = rsqrtf(sq*(1.f/512.f) - mu*mu + 1e-5f);
  float o[8];
  #pragma unroll
  for (int i=0;i<8;i++)
    o[i] = (v[i]-mu)*rs*w[lane*8+i] + b[lane*8+i];
  uint4 st; st.x=pack2(o[0],o[1]); st.y=pack2(o[2],o[3]); st.z=pack2(o[4],o[5]); st.w=pack2(o[6],o[7]);
  *(uint4*)(out + base) = st;
}

// h = LN(ao)*w2+b2 + x (bf16 out) ; z = LN(h)*w3+b3 (bf16 out)
__global__ __launch_bounds__(256) void lnres_kernel(
    const u16* __restrict__ ao, const float* __restrict__ x,
    const float* __restrict__ w2, const float* __restrict__ b2,
    const float* __restrict__ w3, const float* __restrict__ b3,
    u16* __restrict__ h, u16* __restrict__ z)
{
  const int row  = blockIdx.x*4 + (threadIdx.x>>6);
  const int lane = threadIdx.x & 63;
  const size_t base = (size_t)row*512 + lane*8;
  float a[8], xr[8];
  bf8f(*(const uint4*)(ao + base), a);
  { const float4 p = *(const float4*)(x + base);
    const float4 q = *(const float4*)(x + base + 4);
    xr[0]=p.x; xr[1]=p.y; xr[2]=p.z; xr[3]=p.w; xr[4]=q.x; xr[5]=q.y; xr[6]=q.z; xr[7]=q.w; }
  float s=0.f, sq=0.f;
  #pragma unroll
  for (int i=0;i<8;i++){ s += a[i]; sq += a[i]*a[i]; }
  for (int off=32; off>0; off>>=1){ s += __shfl_xor(s, off, 64); sq += __shfl_xor(sq, off, 64); }
  float mu = s*(1.f/512.f);
  float rs = rsqrtf(sq*(1.f/512.f) - mu*mu + 1e-5f);
  float hv[8];
  #pragma unroll
  for (int i=0;i<8;i++)
    hv[i] = (a[i]-mu)*rs*w2[lane*8+i] + b2[lane*8+i] + xr[i];
  { uint4 st; st.x=pack2(hv[0],hv[1]); st.y=pack2(hv[2],hv[3]);
    st.z=pack2(hv[4],hv[5]); st.w=pack2(hv[6],hv[7]);
    *(uint4*)(h + base) = st; }
  s=0.f; sq=0.f;
  #pragma unroll
  for (int i=0;i<8;i++){ s += hv[i]; sq += hv[i]*hv[i]; }
  for (int off=32; off>0; off>>=1){ s += __shfl_xor(s, off, 64); sq += __shfl_xor(sq, off, 64); }
  mu = s*(1.f/512.f);
  rs = rsqrtf(sq*(1.f/512.f) - mu*mu + 1e-5f);
  float zv[8];
  #pragma unroll
  for (int i=0;i<8;i++)
    zv[i] = (hv[i]-mu)*rs*w3[lane*8+i] + b3[lane*8+i];
  uint4 st; st.x=pack2(zv[0],zv[1]); st.y=pack2(zv[2],zv[3]); st.z=pack2(zv[4],zv[5]); st.w=pack2(zv[6],zv[7]);
  *(uint4*)(z + base) = st;
}

// LayerNorm over 2048 (bf16, in place safe)
__global__ __launch_bounds__(256) void ln2048_kernel(
    const u16* x, const float* __restrict__ w, const float* __restrict__ b,
    u16* out)
{
  const int row  = blockIdx.x*4 + (threadIdx.x>>6);
  const int lane = threadIdx.x & 63;
  const u16* xp = x + (size_t)row*2048;
  float v[32];
  #pragma unroll
  for (int g=0; g<4; ++g) bf8f(*(const uint4*)(xp + g*512 + lane*8), v + g*8);
  float s=0.f, sq=0.f;
  #pragma unroll
  for (int i=0;i<32;i++){ s += v[i]; sq += v[i]*v[i]; }
  for (int off=32; off>0; off>>=1){ s += __shfl_xor(s, off, 64); sq += __shfl_xor(sq, off, 64); }
  const float mu = s*(1.f/2048.f);
  const float rs = rsqrtf(sq*(1.f/2048.f) - mu*mu + 1e-5f);
  u16* op = out + (size_t)row*2048;
  #pragma unroll
  for (int g=0; g<4; ++g){
    float o[8];
    #pragma unroll
    for (int i=0;i<8;i++){
      const int idx = g*512 + lane*8 + i;
      o[i] = (v[g*8+i]-mu)*rs*w[idx] + b[idx];
    }
    uint4 st; st.x=pack2(o[0],o[1]); st.y=pack2(o[2],o[3]); st.z=pack2(o[4],o[5]); st.w=pack2(o[6],o[7]);
    *(uint4*)(op + g*512 + lane*8) = st;
  }
}

// ---------------------------------------------------------------------------
// V transpose: QKV[8192 tok][1536] (v at col 1024) -> Vt[bh 64][dim 64][key 1024].
// ---------------------------------------------------------------------------
__global__ __launch_bounds__(256) void transpose_v(
    const u16* __restrict__ QKV, u16* __restrict__ Vt)
{
  __shared__ __align__(16) u16 T[64][72];
  const int bid = blockIdx.x;
  const int bh  = bid >> 4;
  const int kt  = bid & 15;
  const int b   = bh >> 3;
  const int h   = bh & 7;
  const int tid = threadIdx.x;

  const int key = tid >> 2;
  const int dc  = (tid & 3) * 16;
  const u16* src = QKV + ((size_t)(b*1024 + kt*64 + key))*1536 + 1024 + h*64 + dc;
  const uint4 a0 = *(const uint4*)(src);
  const uint4 a1 = *(const uint4*)(src + 8);
  *(uint4*)(&T[key][dc])     = a0;
  *(uint4*)(&T[key][dc + 8]) = a1;
  __syncthreads();

  const int d  = tid >> 2;
  const int kc = (tid & 3) * 16;
  union { uint4 q[2]; u16 us[16]; } ow;
  #pragma unroll
  for (int i=0;i<16;i++) ow.us[i] = T[kc + i][d];
  u16* dst = Vt + ((size_t)(bh*64 + d))*1024 + kt*64 + kc;
  *(uint4*)(dst)     = ow.q[0];
  *(uint4*)(dst + 8) = ow.q[1];
}

// ---------------------------------------------------------------------------
// MFMA differential flash attention — R20 structure, frozen (verified
// 66.4 us): dbuf K+V LDS, 1 barrier/tile, XCD-chunked swizzle, QSCALE'd Q,
// bare v_exp_f32 softmax, single time-shared P buffer (LDS 36864).
// ---------------------------------------------------------------------------
__global__ __launch_bounds__(256) void attn_mfma(
    const u16* __restrict__ QKV, const u16* __restrict__ Vt,
    const float* __restrict__ lq1, const float* __restrict__ lk1,
    const float* __restrict__ lq2, const float* __restrict__ lk2,
    const float* __restrict__ subw, u16* __restrict__ out)
{
  __shared__ __align__(16) u16 Ks1[2][64*32];   // [buf][key][dim 0..31]  8 KB
  __shared__ __align__(16) u16 Ks2[2][64*32];   // [buf][key][dim 32..63] 8 KB
  __shared__ __align__(16) u16 Vs [2][64*64];   // [buf][dim][key 0..63] 16 KB
  __shared__ __align__(16) u16 Ps [4][16*32];   // [wave][row*32]         4 KB

  const int tid  = threadIdx.x;
  const int wave = tid >> 6;
  const int lane = tid & 63;
  const int quad = lane >> 4;
  const int l15  = lane & 15;

  // XCD-chunked swizzle (T1, verified R16: FETCH 69.7->12.4 MB)
  const int bid = blockIdx.x;
  const int bh  = (bid & 7)*8 + ((bid >> 3) >> 4);
  const int qt  = (bid >> 3) & 15;
  const int b   = bh >> 3;
  const int h   = bh & 7;

  float t1 = 0.f, t2 = 0.f;
  for (int i=0;i<32;i++){ t1 += lq1[i]*lk1[i]; t2 += lq2[i]*lk2[i]; }
  const float lam = __expf(t1) - __expf(t2) + 0.2f;   // LAMBDA_INIT = 0.2

  const int qrowg = b*1024 + qt*64 + wave*16 + l15;
  const short8 aq1 = *(const short8*)(QKV + (size_t)qrowg*1536 + 2*h*32 + quad*8);
  const short8 aq2 = *(const short8*)(QKV + (size_t)qrowg*1536 + 2*h*32 + 32 + quad*8);

  floatx4 O1[4] = {}, O2[4] = {};
  float l1acc[4] = {0.f,0.f,0.f,0.f};
  float l2acc[4] = {0.f,0.f,0.f,0.f};
  const floatx4 zf4 = {0.f,0.f,0.f,0.f};

  const int kvbase = b*1024;
  u16* pw = &Ps[wave][0];

  const int kchunk = ((lane&3) ^ ((lane>>3)&3)) * 8;
  const u16* KbaseS = QKV + (size_t)(kvbase + wave*16 + (lane>>2))*1536 + 512 + 2*h*32 + kchunk;
  const int vchunk = ((lane&7) ^ (lane>>3)) * 8;
  const u16* VbaseS = Vt + ((size_t)bh*64 + wave*16 + (lane>>3))*1024 + vchunk;

  #define STAGE_TILE(buf, tt)                                                     \
    do {                                                                          \
      const u16* kp = KbaseS + (size_t)(tt)*64*1536;                              \
      __builtin_amdgcn_global_load_lds(                                           \
          (__attribute__((address_space(1))) void*)(kp),                          \
          (__attribute__((address_space(3))) void*)(&Ks1[buf][wave*16*32]), 16, 0, 0); \
      __builtin_amdgcn_global_load_lds(                                           \
          (__attribute__((address_space(1))) void*)(kp + 32),                     \
          (__attribute__((address_space(3))) void*)(&Ks2[buf][wave*16*32]), 16, 0, 0); \
      const u16* vp = VbaseS + (tt)*64;                                           \
      __builtin_amdgcn_global_load_lds(                                           \
          (__attribute__((address_space(1))) void*)(vp),                          \
          (__attribute__((address_space(3))) void*)(&Vs[buf][wave*16*64]), 16, 0, 0); \
      __builtin_amdgcn_global_load_lds(                                           \
          (__attribute__((address_space(1))) void*)(vp + (size_t)8*1024),         \
          (__attribute__((address_space(3))) void*)(&Vs[buf][(wave*16+8)*64]), 16, 0, 0); \
    } while (0)

  STAGE_TILE(0, 0);
  __syncthreads();

  const int kslotR = (quad ^ ((l15>>1)&3)) * 8;
  const int pslotR = ((quad + (l15>>2)) & 3) * 8;

  for (int t = 0; t < 16; ++t) {
    const int cur = t & 1;

    if (t < 15) STAGE_TILE(cur^1, t+1);

    #pragma unroll
    for (int kh = 0; kh < 2; ++kh) {
      u32 p2h[4];
      #pragma unroll
      for (int ktl = 0; ktl < 2; ++ktl) {
        const int kt = kh*2 + ktl;
        const short8 bk1 = *(const short8*)(&Ks1[cur][(kt*16 + l15)*32 + kslotR]);
        const short8 bk2 = *(const short8*)(&Ks2[cur][(kt*16 + l15)*32 + kslotR]);
        const floatx4 s1 = __builtin_amdgcn_mfma_f32_16x16x32_bf16(aq1, bk1, zf4, 0, 0, 0);
        const floatx4 s2 = __builtin_amdgcn_mfma_f32_16x16x32_bf16(aq2, bk2, zf4, 0, 0, 0);
        const int wslot = ((ktl*2 + (l15>>3) + quad) & 3)*8;
        u16* d1 = pw + wslot + (l15&7);
        float p2v[4];
        #pragma unroll
        for (int rr = 0; rr < 4; ++rr) {
          const float p1 = __builtin_amdgcn_exp2f(s1[rr]);  // Q pre-scaled by SC2
          const float p2 = __builtin_amdgcn_exp2f(s2[rr]);
          d1[(quad*4+rr)*32] = f2bf_fast(p1);
          l1acc[rr] += p1;
          l2acc[rr] += p2;
          p2v[rr] = p2;
        }
        p2h[ktl*2+0] = (u32)f2bf_fast(p2v[0]) | ((u32)f2bf_fast(p2v[1])<<16);
        p2h[ktl*2+1] = (u32)f2bf_fast(p2v[2]) | ((u32)f2bf_fast(p2v[3])<<16);
      }
      // read sub1 A-frag (in-order DS: completes before the P2 overwrites)
      const short8 ap1 = *(const short8*)(pw + l15*32 + pslotR);
      // write sub2 P into the SAME buffer
      #pragma unroll
      for (int ktl = 0; ktl < 2; ++ktl) {
        const int wslot = ((ktl*2 + (l15>>3) + quad) & 3)*8;
        u16* d2 = pw + wslot + (l15&7);
        d2[(quad*4+0)*32] = (u16)(p2h[ktl*2+0] & 0xFFFFu);
        d2[(quad*4+1)*32] = (u16)(p2h[ktl*2+0] >> 16);
        d2[(quad*4+2)*32] = (u16)(p2h[ktl*2+1] & 0xFFFFu);
        d2[(quad*4+3)*32] = (u16)(p2h[ktl*2+1] >> 16);
      }
      const short8 ap2 = *(const short8*)(pw + l15*32 + pslotR);
      const int vslotR = ((kh*4 + quad) ^ (l15&7)) * 8;
      #pragma unroll
      for (int nt = 0; nt < 4; ++nt) {
        const short8 bv = *(const short8*)(&Vs[cur][(nt*16 + l15)*64 + vslotR]);
        O1[nt] = __builtin_amdgcn_mfma_f32_16x16x32_bf16(ap1, bv, O1[nt], 0, 0, 0);
        O2[nt] = __builtin_amdgcn_mfma_f32_16x16x32_bf16(ap2, bv, O2[nt], 0, 0, 0);
      }
    }

    if (t < 15) __syncthreads();
  }
  #undef STAGE_TILE

  #pragma unroll
  for (int rr=0; rr<4; ++rr){
    float v1 = l1acc[rr], v2 = l2acc[rr];
    v1 += __shfl_xor(v1, 1, 64); v2 += __shfl_xor(v2, 1, 64);
    v1 += __shfl_xor(v1, 2, 64); v2 += __shfl_xor(v2, 2, 64);
    v1 += __shfl_xor(v1, 4, 64); v2 += __shfl_xor(v2, 4, 64);
    v1 += __shfl_xor(v1, 8, 64); v2 += __shfl_xor(v2, 8, 64);
    l1acc[rr] = v1; l2acc[rr] = v2;
  }

  float sw[4];
  #pragma unroll
  for (int nt=0; nt<4; ++nt) sw[nt] = subw[nt*16 + l15];

  #pragma unroll
  for (int rr=0; rr<4; ++rr){
    const int row = quad*4 + rr;
    const float il1 = 1.f / l1acc[rr];
    const float cl2 = lam / l2acc[rr];
    float o[4]; float ss = 0.f;
    #pragma unroll
    for (int nt=0; nt<4; ++nt){
      o[nt] = O1[nt][rr]*il1 - O2[nt][rr]*cl2;
      ss += o[nt]*o[nt];
    }
    ss += __shfl_xor(ss, 1, 64);
    ss += __shfl_xor(ss, 2, 64);
    ss += __shfl_xor(ss, 4, 64);
    ss += __shfl_xor(ss, 8, 64);
    const float rs = rsqrtf(ss*(1.f/64.f) + 1e-5f) * 0.8f;
    const int orow = b*1024 + qt*64 + wave*16 + row;
    u16* op = out + (size_t)orow*512 + h*64 + l15;
    #pragma unroll
    for (int nt=0; nt<4; ++nt)
      op[nt*16] = f2bf_fast(o[nt]*rs*sw[nt]);
  }
}

// ---------------------------------------------------------------------------
// Final residual add: out = z2 + h (fp32 out), z2/h bf16 -> done inside
// MLP2 GEMM epilogue (EPI_BIAS_RES reads bf16 h).
// ---------------------------------------------------------------------------
extern "C" void kernel_launch(void* const* d_in, const int* in_sizes, int n_in,
                              void* d_out, int out_size, void* d_ws, size_t ws_size,
                              hipStream_t stream)
{
  (void)in_sizes; (void)n_in; (void)out_size; (void)ws_size;
  const float* x    = (const float*)d_in[0];
  const float* Wq   = (const float*)d_in[1];
  const float* Wk   = (const float*)d_in[2];
  const float* Wv   = (const float*)d_in[3];
  const float* Wo   = (const float*)d_in[4];
  const float* lq1  = (const float*)d_in[5];
  const float* lk1  = (const float*)d_in[6];
  const float* lq2  = (const float*)d_in[7];
  const float* lk2  = (const float*)d_in[8];
  const float* subw = (const float*)d_in[9];
  const float* n1w  = (const float*)d_in[10];
  const float* n1b  = (const float*)d_in[11];
  const float* n2w  = (const float*)d_in[12];
  const float* n2b  = (const float*)d_in[13];
  const float* m1w  = (const float*)d_in[14];
  const float* m1b  = (const float*)d_in[15];
  const float* mW1  = (const float*)d_in[16];
  const float* mb1  = (const float*)d_in[17];
  const float* m2w  = (const float*)d_in[18];
  const float* m2b  = (const float*)d_in[19];
  const float* mW2  = (const float*)d_in[20];
  const float* mb2  = (const float*)d_in[21];
  float* out = (float*)d_out;   // fp32 output

  char* ws = (char*)d_ws;
  const size_t MB = (size_t)1 << 20;
  u16*  xn  = (u16*)(ws + 0*MB);
  u16*  qkv = (u16*)(ws + 8*MB);    // [8192][1536] bf16 = 24 MB -> [8,32)
  u16*  a   = (u16*)(ws + 0*MB);    // attn out, reuse xn
  u16*  ao  = (u16*)(ws + 8*MB);    // reuse qkv (dead after attn)
  u16*  z1  = (u16*)(ws + 16*MB);
  u16*  vt  = (u16*)(ws + 32*MB);   // Vt[64][64][1024] = 16 MB, [32,48)
  u16*  hb  = (u16*)(ws + 40*MB);   // h bf16 8 MB, [40,48) — written AFTER vt dead
  u16*  t   = (u16*)(ws + 48*MB);   // [48,80), LN2048 in place
  u16* Wqkvb= (u16*)(ws + 80*MB);   // [1536][512] bf16 = 1.5 MB
  u16* Wob  = (u16*)(ws + 81*MB + 512*1024);
  u16* W1b  = (u16*)(ws + 82*MB);
  u16* W2b  = (u16*)(ws + 84*MB);

  const int M = 8192;

  cvt_all<<<1536, 256, 0, stream>>>(Wq, Wk, Wv, Wo, mW1, mW2, Wqkvb, Wob, W1b, W2b);

  ln512_kernel<<<2048, 256, 0, stream>>>(x, n1w, n1b, xn);

  gemm_bt<64,EPI_QSCALE,u16><<<dim3(12,128), 256, 0, stream>>>(xn, Wqkvb, nullptr, nullptr, qkv, M, 1536, 512);

  transpose_v<<<1024, 256, 0, stream>>>(qkv, vt);

  attn_mfma<<<1024, 256, 0, stream>>>(qkv, vt, lq1, lk1, lq2, lk2, subw, a);

  gemm_bt<64,EPI_NONE,u16><<<dim3(4,128), 256, 0, stream>>>(a, Wob, nullptr, nullptr, ao, M, 512, 512);

  lnres_kernel<<<2048, 256, 0, stream>>>(ao, x, n2w, n2b, m1w, m1b, hb, z1);

  gemm_bt<64,EPI_BIAS_GELU,u16><<<dim3(16,128), 256, 0, stream>>>(z1, W1b, mb1, nullptr, t, M, 2048, 512);

  ln2048_kernel<<<2048, 256, 0, stream>>>(t, m2w, m2b, t);

  gemm_bt<64,EPI_BIAS_RES,float><<<dim3(4,128), 256, 0, stream>>>(t, W2b, mb2, hb, out, M, 512, 2048);
}

// Round 15
// 307.045 us; speedup vs baseline: 1.0240x; 1.0144x over previous
//
#include <hip/hip_runtime.h>
#include <cstdint>
#include <cstddef>

typedef unsigned short u16;
typedef unsigned int   u32;
typedef __attribute__((ext_vector_type(8))) short short8;
typedef __attribute__((ext_vector_type(4))) float floatx4;

__device__ __forceinline__ float asf(u32 u){ union{u32 u; float f;} v; v.u=u; return v.f; }
__device__ __forceinline__ u32 asu(float f){ union{float f; u32 u;} v; v.f=f; return v.u; }
__device__ __forceinline__ float bf2f(u16 u){ return asf(((u32)u)<<16); }
__device__ __forceinline__ u16 f2bf(float f){ u32 u = asu(f); u32 r = u + 0x7FFFu + ((u>>16)&1u); return (u16)(r>>16); }
// fast bf16: round-to-nearest, ties away (2 VALU ops)
__device__ __forceinline__ u16 f2bf_fast(float f){ return (u16)((asu(f) + 0x8000u)>>16); }
__device__ __forceinline__ u32 pack2(float a, float b){ return (u32)f2bf(a) | (((u32)f2bf(b))<<16); }
__device__ __forceinline__ void bf8f(uint4 d, float* o){
  o[0]=asf(d.x<<16); o[1]=asf(d.x&0xFFFF0000u);
  o[2]=asf(d.y<<16); o[3]=asf(d.y&0xFFFF0000u);
  o[4]=asf(d.z<<16); o[5]=asf(d.z&0xFFFF0000u);
  o[6]=asf(d.w<<16); o[7]=asf(d.w&0xFFFF0000u);
}
// tanh-form GELU via bare v_exp_f32 (max err ~3e-4 vs exact; clamp avoids inf/inf)
__device__ __forceinline__ float gelu_fast(float x){
  const float t = fminf(2.30220771f*(x + 0.044715f*x*x*x), 126.f);
  const float e = __builtin_amdgcn_exp2f(t);
  return x * e / (e + 1.f);
}

#define SC2 0.25503485966f   // 32^-0.5 * log2(e) — folded into Q at QKV epilogue

// ---------------------------------------------------------------------------
// fp32 -> bf16 weight conversion, ALL weights in one launch.
// R22: the W2 segment stores W2*w3 (LN-fold pre-scale).
// ---------------------------------------------------------------------------
__global__ __launch_bounds__(256) void cvt_all(
    const float* __restrict__ Wq, const float* __restrict__ Wk,
    const float* __restrict__ Wv, const float* __restrict__ Wo,
    const float* __restrict__ W1, const float* __restrict__ W2,
    const float* __restrict__ w3,
    u16* __restrict__ Wqkv, u16* __restrict__ Wob,
    u16* __restrict__ W1b, u16* __restrict__ W2b)
{
  const int blk = blockIdx.x;
  const float* src; u16* dst; int off; bool scale = false;
  if      (blk < 128)  { src = Wq; dst = Wqkv;          off = blk; }
  else if (blk < 256)  { src = Wk; dst = Wqkv + 262144; off = blk - 128; }
  else if (blk < 384)  { src = Wv; dst = Wqkv + 524288; off = blk - 256; }
  else if (blk < 512)  { src = Wo; dst = Wob;           off = blk - 384; }
  else if (blk < 1024) { src = W1; dst = W1b;           off = blk - 512; }
  else                 { src = W2; dst = W2b;           off = blk - 1024; scale = true; }
  const int i = (off*256 + threadIdx.x)*8;
  float4 a = *(const float4*)(src + i);
  float4 b = *(const float4*)(src + i + 4);
  if (scale) {
    const int k = i & 2047;                 // W2 row length 2048
    const float4 wa = *(const float4*)(w3 + k);
    const float4 wb = *(const float4*)(w3 + k + 4);
    a.x*=wa.x; a.y*=wa.y; a.z*=wa.z; a.w*=wa.w;
    b.x*=wb.x; b.y*=wb.y; b.z*=wb.z; b.w*=wb.w;
  }
  uint4 st;
  st.x = pack2(a.x, a.y); st.y = pack2(a.z, a.w);
  st.z = pack2(b.x, b.y); st.w = pack2(b.z, b.w);
  *(uint4*)(dst + i) = st;
}

// ---------------------------------------------------------------------------
// c1[n] = sum_k w3[k]*W2[n,k];  c2[n] = sum_k b3[k]*W2[n,k] + mb2[n].
// Interleaved into cbuf[2n], cbuf[2n+1]. Wave-per-n, grid 128 x 4 waves.
// ---------------------------------------------------------------------------
__global__ __launch_bounds__(256) void c12_kernel(
    const float* __restrict__ W2, const float* __restrict__ w3,
    const float* __restrict__ b3, const float* __restrict__ mb2,
    float* __restrict__ cbuf)
{
  const int n    = blockIdx.x*4 + (threadIdx.x>>6);
  const int lane = threadIdx.x & 63;
  const float* row = W2 + (size_t)n*2048 + lane*32;
  const float* w3p = w3 + lane*32;
  const float* b3p = b3 + lane*32;
  float s1 = 0.f, s2 = 0.f;
  #pragma unroll
  for (int i = 0; i < 32; i += 4) {
    const float4 wv = *(const float4*)(row + i);
    const float4 av = *(const float4*)(w3p + i);
    const float4 bv = *(const float4*)(b3p + i);
    s1 += wv.x*av.x + wv.y*av.y + wv.z*av.z + wv.w*av.w;
    s2 += wv.x*bv.x + wv.y*bv.y + wv.z*bv.z + wv.w*bv.w;
  }
  for (int off = 32; off > 0; off >>= 1) {
    s1 += __shfl_xor(s1, off, 64);
    s2 += __shfl_xor(s2, off, 64);
  }
  if (lane == 0) { cbuf[2*n] = s1; cbuf[2*n+1] = s2 + mb2[n]; }
}

// ---------------------------------------------------------------------------
// MFMA GEMM: C[M,N] = A[M,K] @ B[N,K]^T, bf16 in, fp32 accum.
// R19 loop (verified): counted-vmcnt pipeline, 3-buffer LDS, lookahead-1,
// raw s_barrier. Epilogues: QSCALE (Q pre-scale), fast-GELU, bf16-residual,
// R22: EPI_LNFOLD — out = rs_m*(acc - mu_m*c1[n]) + c2[n] + h[m,n].
// ---------------------------------------------------------------------------
enum { EPI_NONE=0, EPI_BIAS_GELU=1, EPI_BIAS_RES=2, EPI_QSCALE=3, EPI_LNFOLD=4 };

template<int BM, int EPI, typename OutT>
__global__ __launch_bounds__(256) void gemm_bt(
    const u16* __restrict__ A, const u16* __restrict__ B,
    const float* __restrict__ bias, const void* __restrict__ res,
    const float* __restrict__ stats,
    OutT* __restrict__ C, int M, int N, int K)
{
  static_assert(BM == 64, "vmcnt literal assumes 3 loads/stage (BM=64)");
  __shared__ u16 As[3][BM*32];
  __shared__ u16 Bs[3][128*32];
  const int tid  = threadIdx.x;
  const int wave = tid >> 6;
  const int lane = tid & 63;
  const int bm = blockIdx.y, bn = blockIdx.x;

  const int srow = wave*16 + (lane>>2);
  const int scol = (lane&3)*8;
  const u16* Ag = A + (size_t)bm*BM*K;
  const u16* Bg = B + (size_t)bn*128*K;

  constexpr int WM = BM/2;          // wave M extent (32)
  constexpr int MI = WM/16;         // A-frag count (2)
  const int wm = (wave>>1)*WM;
  const int wn = (wave&1)*64;
  const int fr = lane & 15;
  const int fk = (lane>>4)*8;

  floatx4 acc[MI][4] = {};

  // 3 loads per stage: 1 x A (64 rows), 2 x B (128 rows)
  #define G_STAGE(buf, kk)                                                        \
    do {                                                                          \
      __builtin_amdgcn_global_load_lds(                                           \
          (__attribute__((address_space(1))) void*)(Ag + (size_t)srow*K + (kk) + scol), \
          (__attribute__((address_space(3))) void*)(&As[buf][wave*16*32]),        \
          16, 0, 0);                                                              \
      _Pragma("unroll")                                                           \
      for (int tt = 0; tt < 2; ++tt)                                              \
        __builtin_amdgcn_global_load_lds(                                         \
            (__attribute__((address_space(1))) void*)(Bg + (size_t)(tt*64 + srow)*K + (kk) + scol), \
            (__attribute__((address_space(3))) void*)(&Bs[buf][(tt*64 + wave*16)*32]),      \
            16, 0, 0);                                                            \
    } while (0)

  // prologue: stage k-step 0 into buf 0
  G_STAGE(0, 0);

  const int nsteps = K >> 5;
  for (int s = 0; s < nsteps; ++s) {
    const int cur = s % 3;
    if (s + 1 < nsteps) {
      G_STAGE((s+1)%3, (s+1)*32);
      // drain own stage(s) (3 oldest); stage(s+1)'s 3 loads stay in flight
      asm volatile("s_waitcnt vmcnt(3)" ::: "memory");
    } else {
      asm volatile("s_waitcnt vmcnt(0)" ::: "memory");
    }
    __builtin_amdgcn_s_barrier();           // raw: no implicit vmcnt(0) drain
    __builtin_amdgcn_sched_barrier(0);      // pin: no ds_read hoisted above

    short8 af[MI], bfr[4];
    #pragma unroll
    for (int i=0;i<MI;i++) af[i] = *(const short8*)(&As[cur][(wm + i*16 + fr)*32 + fk]);
    #pragma unroll
    for (int j=0;j<4;j++) bfr[j] = *(const short8*)(&Bs[cur][(wn + j*16 + fr)*32 + fk]);
    #pragma unroll
    for (int i=0;i<MI;i++)
      #pragma unroll
      for (int j=0;j<4;j++)
        acc[i][j] = __builtin_amdgcn_mfma_f32_16x16x32_bf16(af[i], bfr[j], acc[i][j], 0, 0, 0);
  }
  #undef G_STAGE

  const int col0 = bn*128 + wn + fr;
  float bv[4] = {0.f,0.f,0.f,0.f};
  float c2v[4] = {0.f,0.f,0.f,0.f};
  if constexpr (EPI == EPI_BIAS_GELU || EPI == EPI_BIAS_RES) {
    #pragma unroll
    for (int j=0;j<4;j++) bv[j] = bias[col0 + j*16];
  } else if constexpr (EPI == EPI_LNFOLD) {
    #pragma unroll
    for (int j=0;j<4;j++){ bv[j] = bias[2*(col0 + j*16)]; c2v[j] = bias[2*(col0 + j*16)+1]; }
  }
  const u16* r16 = (const u16*)res;
  const int rq = (lane>>4)*4;
  #pragma unroll
  for (int i=0;i<MI;i++){
    #pragma unroll
    for (int rr=0;rr<4;rr++){
      const int m = bm*BM + wm + i*16 + rq + rr;
      const size_t rowoff = (size_t)m*N;
      float mu = 0.f, rs = 0.f;
      if constexpr (EPI == EPI_LNFOLD){ mu = stats[2*m]; rs = stats[2*m+1]; }
      #pragma unroll
      for (int j=0;j<4;j++){
        float vv = acc[i][j][rr];
        const int n = col0 + j*16;
        if constexpr (EPI == EPI_BIAS_GELU){
          vv = gelu_fast(vv + bv[j]);
        } else if constexpr (EPI == EPI_BIAS_RES){
          vv += bv[j] + bf2f(r16[rowoff + n]);
        } else if constexpr (EPI == EPI_QSCALE){
          if (n < 512) vv *= SC2;   // pre-scale Q so attn uses exp2 directly
        } else if constexpr (EPI == EPI_LNFOLD){
          vv = rs*(vv - mu*bv[j]) + c2v[j] + bf2f(r16[rowoff + n]);
        }
        if constexpr (sizeof(OutT) == 2) C[rowoff + n] = f2bf(vv);
        else                             C[rowoff + n] = vv;
      }
    }
  }
}

// ---------------------------------------------------------------------------
// LayerNorm over 512 (fp32 in, bf16 out), wave-per-row, 4 rows/block
// ---------------------------------------------------------------------------
__global__ __launch_bounds__(256) void ln512_kernel(
    const float* __restrict__ x, const float* __restrict__ w, const float* __restrict__ b,
    u16* __restrict__ out)
{
  const int row  = blockIdx.x*4 + (threadIdx.x>>6);
  const int lane = threadIdx.x & 63;
  const size_t base = (size_t)row*512 + lane*8;
  float v[8];
  { const float4 a = *(const float4*)(x + base);
    const float4 c = *(const float4*)(x + base + 4);
    v[0]=a.x; v[1]=a.y; v[2]=a.z; v[3]=a.w; v[4]=c.x; v[5]=c.y; v[6]=c.z; v[7]=c.w; }
  float s=0.f, sq=0.f;
  #pragma unroll
  for (int i=0;i<8;i++){ s += v[i]; sq += v[i]*v[i]; }
  for (int off=32; off>0; off>>=1){ s += __shfl_xor(s, off, 64); sq += __shfl_xor(sq, off, 64); }
  const float mu = s*(1.f/512.f);
  const float rs = rsqrtf(sq*(1.f/512.f) - mu*mu + 1e-5f);
  float o[8];
  #pragma unroll
  for (int i=0;i<8;i++)
    o[i] = (v[i]-mu)*rs*w[lane*8+i] + b[lane*8+i];
  uint4 st; st.x=pack2(o[0],o[1]); st.y=pack2(o[2],o[3]); st.z=pack2(o[4],o[5]); st.w=pack2(o[6],o[7]);
  *(uint4*)(out + base) = st;
}

// h = LN(ao)*w2+b2 + x (bf16 out) ; z = LN(h)*w3+b3 (bf16 out)
__global__ __launch_bounds__(256) void lnres_kernel(
    const u16* __restrict__ ao, const float* __restrict__ x,
    const float* __restrict__ w2, const float* __restrict__ b2,
    const float* __restrict__ w3, const float* __restrict__ b3,
    u16* __restrict__ h, u16* __restrict__ z)
{
  const int row  = blockIdx.x*4 + (threadIdx.x>>6);
  const int lane = threadIdx.x & 63;
  const size_t base = (size_t)row*512 + lane*8;
  float a[8], xr[8];
  bf8f(*(const uint4*)(ao + base), a);
  { const float4 p = *(const float4*)(x + base);
    const float4 q = *(const float4*)(x + base + 4);
    xr[0]=p.x; xr[1]=p.y; xr[2]=p.z; xr[3]=p.w; xr[4]=q.x; xr[5]=q.y; xr[6]=q.z; xr[7]=q.w; }
  float s=0.f, sq=0.f;
  #pragma unroll
  for (int i=0;i<8;i++){ s += a[i]; sq += a[i]*a[i]; }
  for (int off=32; off>0; off>>=1){ s += __shfl_xor(s, off, 64); sq += __shfl_xor(sq, off, 64); }
  float mu = s*(1.f/512.f);
  float rs = rsqrtf(sq*(1.f/512.f) - mu*mu + 1e-5f);
  float hv[8];
  #pragma unroll
  for (int i=0;i<8;i++)
    hv[i] = (a[i]-mu)*rs*w2[lane*8+i] + b2[lane*8+i] + xr[i];
  { uint4 st; st.x=pack2(hv[0],hv[1]); st.y=pack2(hv[2],hv[3]);
    st.z=pack2(hv[4],hv[5]); st.w=pack2(hv[6],hv[7]);
    *(uint4*)(h + base) = st; }
  s=0.f; sq=0.f;
  #pragma unroll
  for (int i=0;i<8;i++){ s += hv[i]; sq += hv[i]*hv[i]; }
  for (int off=32; off>0; off>>=1){ s += __shfl_xor(s, off, 64); sq += __shfl_xor(sq, off, 64); }
  mu = s*(1.f/512.f);
  rs = rsqrtf(sq*(1.f/512.f) - mu*mu + 1e-5f);
  float zv[8];
  #pragma unroll
  for (int i=0;i<8;i++)
    zv[i] = (hv[i]-mu)*rs*w3[lane*8+i] + b3[lane*8+i];
  uint4 st; st.x=pack2(zv[0],zv[1]); st.y=pack2(zv[2],zv[3]); st.z=pack2(zv[4],zv[5]); st.w=pack2(zv[6],zv[7]);
  *(uint4*)(z + base) = st;
}

// LN-2048 stats only (mu, rs per row -> sbuf[2m], sbuf[2m+1]); the affine
// part is folded into MLP2's epilogue (EPI_LNFOLD). Saves the 32 MB write.
__global__ __launch_bounds__(256) void ln2048_stats(
    const u16* __restrict__ x, float* __restrict__ sbuf)
{
  const int row  = blockIdx.x*4 + (threadIdx.x>>6);
  const int lane = threadIdx.x & 63;
  const u16* xp = x + (size_t)row*2048;
  float v[32];
  #pragma unroll
  for (int g=0; g<4; ++g) bf8f(*(const uint4*)(xp + g*512 + lane*8), v + g*8);
  float s=0.f, sq=0.f;
  #pragma unroll
  for (int i=0;i<32;i++){ s += v[i]; sq += v[i]*v[i]; }
  for (int off=32; off>0; off>>=1){ s += __shfl_xor(s, off, 64); sq += __shfl_xor(sq, off, 64); }
  const float mu = s*(1.f/2048.f);
  const float rs = rsqrtf(sq*(1.f/2048.f) - mu*mu + 1e-5f);
  if (lane == 0) { sbuf[2*row] = mu; sbuf[2*row+1] = rs; }
}

// ---------------------------------------------------------------------------
// V transpose: QKV[8192 tok][1536] (v at col 1024) -> Vt[bh 64][dim 64][key 1024].
// ---------------------------------------------------------------------------
__global__ __launch_bounds__(256) void transpose_v(
    const u16* __restrict__ QKV, u16* __restrict__ Vt)
{
  __shared__ __align__(16) u16 T[64][72];
  const int bid = blockIdx.x;
  const int bh  = bid >> 4;
  const int kt  = bid & 15;
  const int b   = bh >> 3;
  const int h   = bh & 7;
  const int tid = threadIdx.x;

  const int key = tid >> 2;
  const int dc  = (tid & 3) * 16;
  const u16* src = QKV + ((size_t)(b*1024 + kt*64 + key))*1536 + 1024 + h*64 + dc;
  const uint4 a0 = *(const uint4*)(src);
  const uint4 a1 = *(const uint4*)(src + 8);
  *(uint4*)(&T[key][dc])     = a0;
  *(uint4*)(&T[key][dc + 8]) = a1;
  __syncthreads();

  const int d  = tid >> 2;
  const int kc = (tid & 3) * 16;
  union { uint4 q[2]; u16 us[16]; } ow;
  #pragma unroll
  for (int i=0;i<16;i++) ow.us[i] = T[kc + i][d];
  u16* dst = Vt + ((size_t)(bh*64 + d))*1024 + kt*64 + kc;
  *(uint4*)(dst)     = ow.q[0];
  *(uint4*)(dst + 8) = ow.q[1];
}

// ---------------------------------------------------------------------------
// MFMA differential flash attention — R20 structure, frozen (best 66.4 us):
// dbuf K+V LDS, 1 barrier/tile, XCD-chunked swizzle, QSCALE'd Q,
// bare v_exp_f32 softmax, single time-shared P buffer (LDS 36864).
// ---------------------------------------------------------------------------
__global__ __launch_bounds__(256) void attn_mfma(
    const u16* __restrict__ QKV, const u16* __restrict__ Vt,
    const float* __restrict__ lq1, const float* __restrict__ lk1,
    const float* __restrict__ lq2, const float* __restrict__ lk2,
    const float* __restrict__ subw, u16* __restrict__ out)
{
  __shared__ __align__(16) u16 Ks1[2][64*32];   // [buf][key][dim 0..31]  8 KB
  __shared__ __align__(16) u16 Ks2[2][64*32];   // [buf][key][dim 32..63] 8 KB
  __shared__ __align__(16) u16 Vs [2][64*64];   // [buf][dim][key 0..63] 16 KB
  __shared__ __align__(16) u16 Ps [4][16*32];   // [wave][row*32]         4 KB

  const int tid  = threadIdx.x;
  const int wave = tid >> 6;
  const int lane = tid & 63;
  const int quad = lane >> 4;
  const int l15  = lane & 15;

  // XCD-chunked swizzle (T1, verified R16: FETCH 69.7->12.4 MB)
  const int bid = blockIdx.x;
  const int bh  = (bid & 7)*8 + ((bid >> 3) >> 4);
  const int qt  = (bid >> 3) & 15;
  const int b   = bh >> 3;
  const int h   = bh & 7;

  float t1 = 0.f, t2 = 0.f;
  for (int i=0;i<32;i++){ t1 += lq1[i]*lk1[i]; t2 += lq2[i]*lk2[i]; }
  const float lam = __expf(t1) - __expf(t2) + 0.2f;   // LAMBDA_INIT = 0.2

  const int qrowg = b*1024 + qt*64 + wave*16 + l15;
  const short8 aq1 = *(const short8*)(QKV + (size_t)qrowg*1536 + 2*h*32 + quad*8);
  const short8 aq2 = *(const short8*)(QKV + (size_t)qrowg*1536 + 2*h*32 + 32 + quad*8);

  floatx4 O1[4] = {}, O2[4] = {};
  float l1acc[4] = {0.f,0.f,0.f,0.f};
  float l2acc[4] = {0.f,0.f,0.f,0.f};
  const floatx4 zf4 = {0.f,0.f,0.f,0.f};

  const int kvbase = b*1024;
  u16* pw = &Ps[wave][0];

  const int kchunk = ((lane&3) ^ ((lane>>3)&3)) * 8;
  const u16* KbaseS = QKV + (size_t)(kvbase + wave*16 + (lane>>2))*1536 + 512 + 2*h*32 + kchunk;
  const int vchunk = ((lane&7) ^ (lane>>3)) * 8;
  const u16* VbaseS = Vt + ((size_t)bh*64 + wave*16 + (lane>>3))*1024 + vchunk;

  #define STAGE_TILE(buf, tt)                                                     \
    do {                                                                          \
      const u16* kp = KbaseS + (size_t)(tt)*64*1536;                              \
      __builtin_amdgcn_global_load_lds(                                           \
          (__attribute__((address_space(1))) void*)(kp),                          \
          (__attribute__((address_space(3))) void*)(&Ks1[buf][wave*16*32]), 16, 0, 0); \
      __builtin_amdgcn_global_load_lds(                                           \
          (__attribute__((address_space(1))) void*)(kp + 32),                     \
          (__attribute__((address_space(3))) void*)(&Ks2[buf][wave*16*32]), 16, 0, 0); \
      const u16* vp = VbaseS + (tt)*64;                                           \
      __builtin_amdgcn_global_load_lds(                                           \
          (__attribute__((address_space(1))) void*)(vp),                          \
          (__attribute__((address_space(3))) void*)(&Vs[buf][wave*16*64]), 16, 0, 0); \
      __builtin_amdgcn_global_load_lds(                                           \
          (__attribute__((address_space(1))) void*)(vp + (size_t)8*1024),         \
          (__attribute__((address_space(3))) void*)(&Vs[buf][(wave*16+8)*64]), 16, 0, 0); \
    } while (0)

  STAGE_TILE(0, 0);
  __syncthreads();

  const int kslotR = (quad ^ ((l15>>1)&3)) * 8;
  const int pslotR = ((quad + (l15>>2)) & 3) * 8;

  for (int t = 0; t < 16; ++t) {
    const int cur = t & 1;

    if (t < 15) STAGE_TILE(cur^1, t+1);

    #pragma unroll
    for (int kh = 0; kh < 2; ++kh) {
      u32 p2h[4];
      #pragma unroll
      for (int ktl = 0; ktl < 2; ++ktl) {
        const int kt = kh*2 + ktl;
        const short8 bk1 = *(const short8*)(&Ks1[cur][(kt*16 + l15)*32 + kslotR]);
        const short8 bk2 = *(const short8*)(&Ks2[cur][(kt*16 + l15)*32 + kslotR]);
        const floatx4 s1 = __builtin_amdgcn_mfma_f32_16x16x32_bf16(aq1, bk1, zf4, 0, 0, 0);
        const floatx4 s2 = __builtin_amdgcn_mfma_f32_16x16x32_bf16(aq2, bk2, zf4, 0, 0, 0);
        const int wslot = ((ktl*2 + (l15>>3) + quad) & 3)*8;
        u16* d1 = pw + wslot + (l15&7);
        float p2v[4];
        #pragma unroll
        for (int rr = 0; rr < 4; ++rr) {
          const float p1 = __builtin_amdgcn_exp2f(s1[rr]);  // Q pre-scaled by SC2
          const float p2 = __builtin_amdgcn_exp2f(s2[rr]);
          d1[(quad*4+rr)*32] = f2bf_fast(p1);
          l1acc[rr] += p1;
          l2acc[rr] += p2;
          p2v[rr] = p2;
        }
        p2h[ktl*2+0] = (u32)f2bf_fast(p2v[0]) | ((u32)f2bf_fast(p2v[1])<<16);
        p2h[ktl*2+1] = (u32)f2bf_fast(p2v[2]) | ((u32)f2bf_fast(p2v[3])<<16);
      }
      // read sub1 A-frag (in-order DS: completes before the P2 overwrites)
      const short8 ap1 = *(const short8*)(pw + l15*32 + pslotR);
      // write sub2 P into the SAME buffer
      #pragma unroll
      for (int ktl = 0; ktl < 2; ++ktl) {
        const int wslot = ((ktl*2 + (l15>>3) + quad) & 3)*8;
        u16* d2 = pw + wslot + (l15&7);
        d2[(quad*4+0)*32] = (u16)(p2h[ktl*2+0] & 0xFFFFu);
        d2[(quad*4+1)*32] = (u16)(p2h[ktl*2+0] >> 16);
        d2[(quad*4+2)*32] = (u16)(p2h[ktl*2+1] & 0xFFFFu);
        d2[(quad*4+3)*32] = (u16)(p2h[ktl*2+1] >> 16);
      }
      const short8 ap2 = *(const short8*)(pw + l15*32 + pslotR);
      const int vslotR = ((kh*4 + quad) ^ (l15&7)) * 8;
      #pragma unroll
      for (int nt = 0; nt < 4; ++nt) {
        const short8 bv = *(const short8*)(&Vs[cur][(nt*16 + l15)*64 + vslotR]);
        O1[nt] = __builtin_amdgcn_mfma_f32_16x16x32_bf16(ap1, bv, O1[nt], 0, 0, 0);
        O2[nt] = __builtin_amdgcn_mfma_f32_16x16x32_bf16(ap2, bv, O2[nt], 0, 0, 0);
      }
    }

    if (t < 15) __syncthreads();
  }
  #undef STAGE_TILE

  #pragma unroll
  for (int rr=0; rr<4; ++rr){
    float v1 = l1acc[rr], v2 = l2acc[rr];
    v1 += __shfl_xor(v1, 1, 64); v2 += __shfl_xor(v2, 1, 64);
    v1 += __shfl_xor(v1, 2, 64); v2 += __shfl_xor(v2, 2, 64);
    v1 += __shfl_xor(v1, 4, 64); v2 += __shfl_xor(v2, 4, 64);
    v1 += __shfl_xor(v1, 8, 64); v2 += __shfl_xor(v2, 8, 64);
    l1acc[rr] = v1; l2acc[rr] = v2;
  }

  float sw[4];
  #pragma unroll
  for (int nt=0; nt<4; ++nt) sw[nt] = subw[nt*16 + l15];

  #pragma unroll
  for (int rr=0; rr<4; ++rr){
    const int row = quad*4 + rr;
    const float il1 = 1.f / l1acc[rr];
    const float cl2 = lam / l2acc[rr];
    float o[4]; float ss = 0.f;
    #pragma unroll
    for (int nt=0; nt<4; ++nt){
      o[nt] = O1[nt][rr]*il1 - O2[nt][rr]*cl2;
      ss += o[nt]*o[nt];
    }
    ss += __shfl_xor(ss, 1, 64);
    ss += __shfl_xor(ss, 2, 64);
    ss += __shfl_xor(ss, 4, 64);
    ss += __shfl_xor(ss, 8, 64);
    const float rs = rsqrtf(ss*(1.f/64.f) + 1e-5f) * 0.8f;
    const int orow = b*1024 + qt*64 + wave*16 + row;
    u16* op = out + (size_t)orow*512 + h*64 + l15;
    #pragma unroll
    for (int nt=0; nt<4; ++nt)
      op[nt*16] = f2bf_fast(o[nt]*rs*sw[nt]);
  }
}

// ---------------------------------------------------------------------------
extern "C" void kernel_launch(void* const* d_in, const int* in_sizes, int n_in,
                              void* d_out, int out_size, void* d_ws, size_t ws_size,
                              hipStream_t stream)
{
  (void)in_sizes; (void)n_in; (void)out_size; (void)ws_size;
  const float* x    = (const float*)d_in[0];
  const float* Wq   = (const float*)d_in[1];
  const float* Wk   = (const float*)d_in[2];
  const float* Wv   = (const float*)d_in[3];
  const float* Wo   = (const float*)d_in[4];
  const float* lq1  = (const float*)d_in[5];
  const float* lk1  = (const float*)d_in[6];
  const float* lq2  = (const float*)d_in[7];
  const float* lk2  = (const float*)d_in[8];
  const float* subw = (const float*)d_in[9];
  const float* n1w  = (const float*)d_in[10];
  const float* n1b  = (const float*)d_in[11];
  const float* n2w  = (const float*)d_in[12];
  const float* n2b  = (const float*)d_in[13];
  const float* m1w  = (const float*)d_in[14];
  const float* m1b  = (const float*)d_in[15];
  const float* mW1  = (const float*)d_in[16];
  const float* mb1  = (const float*)d_in[17];
  const float* m2w  = (const float*)d_in[18];
  const float* m2b  = (const float*)d_in[19];
  const float* mW2  = (const float*)d_in[20];
  const float* mb2  = (const float*)d_in[21];
  float* out = (float*)d_out;   // fp32 output

  char* ws = (char*)d_ws;
  const size_t MB = (size_t)1 << 20;
  u16*  xn  = (u16*)(ws + 0*MB);
  u16*  qkv = (u16*)(ws + 8*MB);    // [8192][1536] bf16 = 24 MB -> [8,32)
  u16*  a   = (u16*)(ws + 0*MB);    // attn out, reuse xn
  u16*  ao  = (u16*)(ws + 8*MB);    // reuse qkv (dead after attn)
  u16*  z1  = (u16*)(ws + 16*MB);
  u16*  vt  = (u16*)(ws + 32*MB);   // Vt 8 MB, [32,40)
  u16*  hb  = (u16*)(ws + 40*MB);   // h bf16 8 MB, [40,48)
  u16*  t   = (u16*)(ws + 48*MB);   // MLP1 out 32 MB, [48,80)
  u16* Wqkvb= (u16*)(ws + 80*MB);
  u16* Wob  = (u16*)(ws + 81*MB + 512*1024);
  u16* W1b  = (u16*)(ws + 82*MB);
  u16* W2b  = (u16*)(ws + 84*MB);   // pre-scaled by m2w (w3)
  float* sbuf = (float*)(ws + 86*MB);          // [8192][2] mu,rs = 64 KB
  float* cbuf = (float*)(ws + 86*MB + 65536);  // [512][2]  c1,c2 = 4 KB

  const int M = 8192;

  cvt_all<<<1536, 256, 0, stream>>>(Wq, Wk, Wv, Wo, mW1, mW2, m2w, Wqkvb, Wob, W1b, W2b);

  c12_kernel<<<128, 256, 0, stream>>>(mW2, m2w, m2b, mb2, cbuf);

  ln512_kernel<<<2048, 256, 0, stream>>>(x, n1w, n1b, xn);

  gemm_bt<64,EPI_QSCALE,u16><<<dim3(12,128), 256, 0, stream>>>(xn, Wqkvb, nullptr, nullptr, nullptr, qkv, M, 1536, 512);

  transpose_v<<<1024, 256, 0, stream>>>(qkv, vt);

  attn_mfma<<<1024, 256, 0, stream>>>(qkv, vt, lq1, lk1, lq2, lk2, subw, a);

  gemm_bt<64,EPI_NONE,u16><<<dim3(4,128), 256, 0, stream>>>(a, Wob, nullptr, nullptr, nullptr, ao, M, 512, 512);

  lnres_kernel<<<2048, 256, 0, stream>>>(ao, x, n2w, n2b, m1w, m1b, hb, z1);

  gemm_bt<64,EPI_BIAS_GELU,u16><<<dim3(16,128), 256, 0, stream>>>(z1, W1b, mb1, nullptr, nullptr, t, M, 2048, 512);

  ln2048_stats<<<2048, 256, 0, stream>>>(t, sbuf);

  gemm_bt<64,EPI_LNFOLD,float><<<dim3(4,128), 256, 0, stream>>>(t, W2b, cbuf, hb, sbuf, out, M, 512, 2048);
}